// Round 4
// baseline (776.181 us; speedup 1.0000x reference)
//
#include <hip/hip_runtime.h>
#include <hip/hip_bf16.h>

typedef __bf16 bf16x8 __attribute__((ext_vector_type(8)));
typedef float  f32x4  __attribute__((ext_vector_type(4)));

#define MFMA16(a,b,c) __builtin_amdgcn_mfma_f32_16x16x32_bf16((a),(b),(c),0,0,0)

__device__ __forceinline__ bf16x8 cvt8(f32x4 a, f32x4 b){
  bf16x8 r;
  r[0]=(__bf16)a[0]; r[1]=(__bf16)a[1]; r[2]=(__bf16)a[2]; r[3]=(__bf16)a[3];
  r[4]=(__bf16)b[0]; r[5]=(__bf16)b[1]; r[6]=(__bf16)b[2]; r[7]=(__bf16)b[3];
  return r;
}
__device__ __forceinline__ bf16x8 ld8(const float* p){
  return cvt8(*(const f32x4*)p, *(const f32x4*)(p+4));
}
__device__ __forceinline__ float sigm(float x){
  return __builtin_amdgcn_rcpf(1.f + __expf(-x));
}
__device__ __forceinline__ float tanhx(float x){
  return 1.f - 2.f*__builtin_amdgcn_rcpf(1.f + __expf(2.f*x));
}

extern "C" __global__ void __launch_bounds__(512, 1)   // 1 block/CU, 8 waves (2/SIMD)
seq2seq_kernel(const float* __restrict__ X,
               const float* __restrict__ Wemb, const float* __restrict__ bemb,
               const float* __restrict__ eWih, const float* __restrict__ eWhh,
               const float* __restrict__ ebih, const float* __restrict__ ebhh,
               const float* __restrict__ dWih, const float* __restrict__ dWhh,
               const float* __restrict__ dbih, const float* __restrict__ dbhh,
               const float* __restrict__ Wreg, const float* __restrict__ breg,
               float* __restrict__ out)
{
  // 8 real batch rows/block. XH: cols 0..63 = x (bf16), 64..127 = h.
  // Row stride 144 elems (72 dw = 8 mod 32): scalar writes 2-way max, b128 reads clean.
  __shared__ __align__(16) __bf16 XH0[8][144];
  __shared__ __align__(16) __bf16 XH1[8][144];
  // Gate exchange buffers, f32, row stride 264 (8 mod 32): writes 2-way, reads 2-way.
  __shared__ __align__(16) float G0[8][264];
  __shared__ __align__(16) float G1[8][264];

  const int tid  = (int)threadIdx.x;
  const int w    = tid >> 6;          // wave 0..7
  const int lane = tid & 63;
  const int col  = lane & 15;
  const int quad = lane >> 4;
  const int row8 = col & 7;           // A-matrix real row (M=16 mirrors 8 rows)
  const int b0   = (int)blockIdx.x * 8;
  const int brow = b0 + row8;

  for (int i = tid; i < 8*144; i += 512){
    (&XH0[0][0])[i] = (__bf16)0.f;
    (&XH1[0][0])[i] = (__bf16)0.f;
  }

  // wave owns gate n-tiles {2w, 2w+1}: gate columns n0, n1 in [0,256)
  const int n0 = 32*w + col;
  const int n1 = n0 + 16;

  // embedding frag (waves 0..3 use it; tile = w&3)
  const int ue = (w&3)*16 + col;
  bf16x8 wembf = ld8(Wemb + ue*32 + quad*8);
  const float eb = bemb[ue];

  // regression head (wave 0 uses it)
  bf16x8 wr[2];
#pragma unroll
  for (int ks=0; ks<2; ++ks) wr[ks] = ld8(Wreg + (col&7)*64 + ks*32 + quad*8);
  const float rb = breg[col&7];

  // gate weight B-frags: 2 layers x 2 tiles x 4 ksteps = 64 VGPRs
  bf16x8 wf[2][2][4];
  float  gbias[2][2];
#pragma unroll
  for (int l=0; l<2; ++l){
#pragma unroll
    for (int ti=0; ti<2; ++ti){
      const int n = ti ? n1 : n0;
      gbias[l][ti] = ebih[l*256+n] + ebhh[l*256+n];
#pragma unroll
      for (int ks=0; ks<4; ++ks){
        const float* srcw = (ks < 2) ? eWih : eWhh;
        wf[l][ti][ks] = ld8(srcw + ((size_t)(l*256+n))*64 + (ks&1)*32 + quad*8);
      }
    }
  }

  float c0 = 0.f, c1 = 0.f;
  const float* xb = X + (size_t)brow*512*32 + quad*8;
  f32x4 pa[2], pb[2];

  __syncthreads();                       // zero-init visible

  if (w < 4){
    // emb(0) + prefetch X(1)->slot1, X(2)->slot0
    f32x4 xa = *(const f32x4*)xb, xv = *(const f32x4*)(xb+4);
    pa[1] = *(const f32x4*)(xb+32); pb[1] = *(const f32x4*)(xb+36);
    pa[0] = *(const f32x4*)(xb+64); pb[0] = *(const f32x4*)(xb+68);
    f32x4 ea = (f32x4){eb,eb,eb,eb};
    ea = MFMA16(cvt8(xa,xv), wembf, ea);
    if (quad < 2){
#pragma unroll
      for (int r=0; r<4; ++r) XH0[quad*4+r][ue] = (__bf16)ea[r];
    }
  }
  __syncthreads();

  // ================= encoder: 3 barriers/t =================
#pragma unroll 2
  for (int t=0; t<512; ++t){
    // P1: L0 gates GEMM -> G0
    {
      bf16x8 afr[4];
#pragma unroll
      for (int ks=0; ks<4; ++ks)
        afr[ks] = *(const bf16x8*)&XH0[row8][ks*32 + quad*8];
      f32x4 a0 = (f32x4){gbias[0][0],gbias[0][0],gbias[0][0],gbias[0][0]};
      f32x4 a1 = (f32x4){gbias[0][1],gbias[0][1],gbias[0][1],gbias[0][1]};
#pragma unroll
      for (int ks=0; ks<4; ++ks){
        a0 = MFMA16(afr[ks], wf[0][0][ks], a0);
        a1 = MFMA16(afr[ks], wf[0][1][ks], a1);
      }
      if (quad < 2){
#pragma unroll
        for (int r=0; r<4; ++r){ G0[quad*4+r][n0] = a0[r]; G0[quad*4+r][n1] = a1[r]; }
      }
    }
    __syncthreads();                     // B1: G0 ready; XH0 reads done
    // P2: L0 elementwise (cell = row w, unit lane) + emb(t+1)
    {
      float gi = sigm (G0[w][lane]);
      float gf = sigm (G0[w][64+lane]);
      float gg = tanhx(G0[w][128+lane]);
      float go = sigm (G0[w][192+lane]);
      c0 = gf*c0 + gi*gg;
      __bf16 hb = (__bf16)(go * tanhx(c0));
      XH0[w][64+lane] = hb;              // h0 recurrent
      XH1[w][lane]    = hb;              // L1 input
      if (w < 4){
        const int s = (t+1)&1;
        f32x4 ea = (f32x4){eb,eb,eb,eb};
        ea = MFMA16(cvt8(pa[s],pb[s]), wembf, ea);
        int tn = t+3; if (tn > 511) tn = 511;
        pa[s] = *(const f32x4*)(xb + (size_t)tn*32);
        pb[s] = *(const f32x4*)(xb + (size_t)tn*32 + 4);
        if (quad < 2){
#pragma unroll
          for (int r=0; r<4; ++r) XH0[quad*4+r][ue] = (__bf16)ea[r];
        }
      }
    }
    __syncthreads();                     // B2: h0/x/emb visible
    // P3: L1 gates GEMM -> G1
    {
      bf16x8 afr[4];
#pragma unroll
      for (int ks=0; ks<4; ++ks)
        afr[ks] = *(const bf16x8*)&XH1[row8][ks*32 + quad*8];
      f32x4 a0 = (f32x4){gbias[1][0],gbias[1][0],gbias[1][0],gbias[1][0]};
      f32x4 a1 = (f32x4){gbias[1][1],gbias[1][1],gbias[1][1],gbias[1][1]};
#pragma unroll
      for (int ks=0; ks<4; ++ks){
        a0 = MFMA16(afr[ks], wf[1][0][ks], a0);
        a1 = MFMA16(afr[ks], wf[1][1][ks], a1);
      }
      if (quad < 2){
#pragma unroll
        for (int r=0; r<4; ++r){ G1[quad*4+r][n0] = a0[r]; G1[quad*4+r][n1] = a1[r]; }
      }
    }
    __syncthreads();                     // B3: G1 ready; XH1 reads done
    // P4: L1 elementwise (no trailing barrier; next P1 touches neither G1 nor XH1)
    {
      float gi = sigm (G1[w][lane]);
      float gf = sigm (G1[w][64+lane]);
      float gg = tanhx(G1[w][128+lane]);
      float go = sigm (G1[w][192+lane]);
      c1 = gf*c1 + gi*gg;
      XH1[w][64+lane] = (__bf16)(go * tanhx(c1));
    }
  }
  __syncthreads();                       // final h1 writes visible

  // ---- decoder init: L0 input = h1_enc; recurrent h stays; c = 0 ----
  {
    int r = tid >> 6, cc = tid & 63;
    XH0[r][cc] = XH1[r][64 + cc];
  }
#pragma unroll
  for (int l=0; l<2; ++l){
#pragma unroll
    for (int ti=0; ti<2; ++ti){
      const int n = ti ? n1 : n0;
      gbias[l][ti] = dbih[l*256+n] + dbhh[l*256+n];
#pragma unroll
      for (int ks=0; ks<4; ++ks){
        const float* srcw = (ks < 2) ? dWih : dWhh;
        wf[l][ti][ks] = ld8(srcw + ((size_t)(l*256+n))*64 + (ks&1)*32 + quad*8);
      }
    }
  }
  c0 = 0.f; c1 = 0.f;
  __syncthreads();

  // ================= decoder: 4 barriers/t =================
  for (int t=0; t<48; ++t){
    // P1: L0 GEMM -> G0
    {
      bf16x8 afr[4];
#pragma unroll
      for (int ks=0; ks<4; ++ks)
        afr[ks] = *(const bf16x8*)&XH0[row8][ks*32 + quad*8];
      f32x4 a0 = (f32x4){gbias[0][0],gbias[0][0],gbias[0][0],gbias[0][0]};
      f32x4 a1 = (f32x4){gbias[0][1],gbias[0][1],gbias[0][1],gbias[0][1]};
#pragma unroll
      for (int ks=0; ks<4; ++ks){
        a0 = MFMA16(afr[ks], wf[0][0][ks], a0);
        a1 = MFMA16(afr[ks], wf[0][1][ks], a1);
      }
      if (quad < 2){
#pragma unroll
        for (int r=0; r<4; ++r){ G0[quad*4+r][n0] = a0[r]; G0[quad*4+r][n1] = a1[r]; }
      }
    }
    __syncthreads();                     // B1
    {
      float gi = sigm (G0[w][lane]);
      float gf = sigm (G0[w][64+lane]);
      float gg = tanhx(G0[w][128+lane]);
      float go = sigm (G0[w][192+lane]);
      c0 = gf*c0 + gi*gg;
      __bf16 hb = (__bf16)(go * tanhx(c0));
      XH0[w][64+lane] = hb;
      XH1[w][lane]    = hb;
    }
    __syncthreads();                     // B2
    // P3: L1 GEMM -> G1
    {
      bf16x8 afr[4];
#pragma unroll
      for (int ks=0; ks<4; ++ks)
        afr[ks] = *(const bf16x8*)&XH1[row8][ks*32 + quad*8];
      f32x4 a0 = (f32x4){gbias[1][0],gbias[1][0],gbias[1][0],gbias[1][0]};
      f32x4 a1 = (f32x4){gbias[1][1],gbias[1][1],gbias[1][1],gbias[1][1]};
#pragma unroll
      for (int ks=0; ks<4; ++ks){
        a0 = MFMA16(afr[ks], wf[1][0][ks], a0);
        a1 = MFMA16(afr[ks], wf[1][1][ks], a1);
      }
      if (quad < 2){
#pragma unroll
        for (int r=0; r<4; ++r){ G1[quad*4+r][n0] = a0[r]; G1[quad*4+r][n1] = a1[r]; }
      }
    }
    __syncthreads();                     // B3
    {
      float gi = sigm (G1[w][lane]);
      float gf = sigm (G1[w][64+lane]);
      float gg = tanhx(G1[w][128+lane]);
      float go = sigm (G1[w][192+lane]);
      c1 = gf*c1 + gi*gg;
      __bf16 hb = (__bf16)(go * tanhx(c1));
      XH1[w][64+lane] = hb;
      XH0[w][lane]    = hb;              // h[-1] feedback -> next L0 input
    }
    __syncthreads();                     // B4: h1 visible for y-head & next P1
    // P5: y = h1 @ Wreg^T + breg (wave 0 only; no LDS writes -> no extra barrier)
    if (w == 0){
      f32x4 ya = (f32x4){rb,rb,rb,rb};
#pragma unroll
      for (int ks=0; ks<2; ++ks){
        bf16x8 ah = *(const bf16x8*)&XH1[row8][64 + ks*32 + quad*8];
        ya = MFMA16(ah, wr[ks], ya);
      }
      if (quad < 2 && col < 8){
#pragma unroll
        for (int r=0; r<4; ++r)
          out[((size_t)(b0 + quad*4 + r)*48 + t)*8 + col] = ya[r];
      }
    }
  }
}

extern "C" void kernel_launch(void* const* d_in, const int* in_sizes, int n_in,
                              void* d_out, int out_size, void* d_ws, size_t ws_size,
                              hipStream_t stream)
{
  (void)in_sizes; (void)n_in; (void)out_size; (void)d_ws; (void)ws_size;
  const float* X    = (const float*)d_in[0];
  const float* Wemb = (const float*)d_in[2];
  const float* bemb = (const float*)d_in[3];
  const float* eWih = (const float*)d_in[4];
  const float* eWhh = (const float*)d_in[5];
  const float* ebih = (const float*)d_in[6];
  const float* ebhh = (const float*)d_in[7];
  const float* dWih = (const float*)d_in[8];
  const float* dWhh = (const float*)d_in[9];
  const float* dbih = (const float*)d_in[10];
  const float* dbhh = (const float*)d_in[11];
  const float* Wreg = (const float*)d_in[12];
  const float* breg = (const float*)d_in[13];
  float* out = (float*)d_out;

  seq2seq_kernel<<<dim3(256), dim3(512), 0, stream>>>(
      X, Wemb, bemb, eWih, eWhh, ebih, ebhh,
      dWih, dWhh, dbih, dbhh, Wreg, breg, out);
}

// Round 5
// 709.452 us; speedup vs baseline: 1.0941x; 1.0941x over previous
//
#include <hip/hip_runtime.h>
#include <hip/hip_bf16.h>

typedef __bf16 bf16x8 __attribute__((ext_vector_type(8)));
typedef float  f32x4  __attribute__((ext_vector_type(4)));

#define MFMA16(a,b,c) __builtin_amdgcn_mfma_f32_16x16x32_bf16((a),(b),(c),0,0,0)

__device__ __forceinline__ bf16x8 cvt8(f32x4 a, f32x4 b){
  bf16x8 r;
  r[0]=(__bf16)a[0]; r[1]=(__bf16)a[1]; r[2]=(__bf16)a[2]; r[3]=(__bf16)a[3];
  r[4]=(__bf16)b[0]; r[5]=(__bf16)b[1]; r[6]=(__bf16)b[2]; r[7]=(__bf16)b[3];
  return r;
}
__device__ __forceinline__ bf16x8 ld8(const float* p){
  return cvt8(*(const f32x4*)p, *(const f32x4*)(p+4));
}
__device__ __forceinline__ float sigm(float x){
  return __builtin_amdgcn_rcpf(1.f + __expf(-x));
}
__device__ __forceinline__ float tanhx(float x){
  return 1.f - 2.f*__builtin_amdgcn_rcpf(1.f + __expf(2.f*x));
}
__device__ __forceinline__ f32x4 sp(float v){ return (f32x4){v,v,v,v}; }

extern "C" __global__ void __launch_bounds__(512, 1)   // 8 waves, 2/SIMD
seq2seq_kernel(const float* __restrict__ X,
               const float* __restrict__ Wemb, const float* __restrict__ bemb,
               const float* __restrict__ eWih, const float* __restrict__ eWhh,
               const float* __restrict__ ebih, const float* __restrict__ ebhh,
               const float* __restrict__ dWih, const float* __restrict__ dWhh,
               const float* __restrict__ dbih, const float* __restrict__ dbhh,
               const float* __restrict__ Wreg, const float* __restrict__ breg,
               float* __restrict__ out)
{
  // XA: cols 0..63 = x/input, 64..127 = h0, 128..191 = h1 (bf16).
  // Row stride 208 bf16 = 104 dw = 8 mod 32 (same conflict class as R4: <=2-way).
  // Double-buffered by iteration parity for the encoder pipeline.
  __shared__ __align__(16) __bf16 XA[2][8][208];
  __shared__ __align__(16) float GL0[8][264];   // 264 = 8 mod 32
  __shared__ __align__(16) float GL1[8][264];

  const int tid  = (int)threadIdx.x;
  const int w    = tid >> 6;          // wave 0..7
  const int lane = tid & 63;
  const int col  = lane & 15;
  const int quad = lane >> 4;
  const int row8 = col & 7;           // A real row (M=16 mirrors 8 rows)
  const int b0   = (int)blockIdx.x * 8;
  const int brow = b0 + row8;

  const int n0 = 32*w + col;          // wave owns gate cols {n0, n0+16}
  const int n1 = n0 + 16;

#define AFR(P,BASE,KS) (*(const bf16x8*)&XA[P][row8][(BASE) + (KS)*32 + quad*8])

  for (int idx = tid; idx < 2*8*208; idx += 512)
    (&XA[0][0][0])[idx] = (__bf16)0.f;

  // ---- persistent fragments ----
  const int ue = (w&3)*16 + col;                 // emb unit (waves 0..3)
  bf16x8 wembf = ld8(Wemb + ue*32 + quad*8);
  const float eb = bemb[ue];

  bf16x8 wr[2];
#pragma unroll
  for (int ks=0; ks<2; ++ks) wr[ks] = ld8(Wreg + (col&7)*64 + ks*32 + quad*8);
  const float rb = breg[col&7];

  bf16x8 wf[2][2][4];
  float  gbias[2][2];
#pragma unroll
  for (int l=0; l<2; ++l)
#pragma unroll
    for (int ti=0; ti<2; ++ti){
      const int n = ti ? n1 : n0;
      gbias[l][ti] = ebih[l*256+n] + ebhh[l*256+n];
#pragma unroll
      for (int ks=0; ks<4; ++ks){
        const float* srcw = (ks < 2) ? eWih : eWhh;
        wf[l][ti][ks] = ld8(srcw + ((size_t)(l*256+n))*64 + (ks&1)*32 + quad*8);
      }
    }

  float c0 = 0.f, c1 = 0.f;
  const float* xb = X + (size_t)brow*512*32 + quad*8;

  // x(0), x(1) direct; slot0 = x(2), slot1 = x(3)
  f32x4 x0a = *(const f32x4*)(xb),     x0b = *(const f32x4*)(xb+4);
  f32x4 x1a = *(const f32x4*)(xb+32),  x1b = *(const f32x4*)(xb+36);
  f32x4 pa[2], pb[2];
  pa[0] = *(const f32x4*)(xb+64);  pb[0] = *(const f32x4*)(xb+68);
  pa[1] = *(const f32x4*)(xb+96);  pb[1] = *(const f32x4*)(xb+100);

  __syncthreads();                    // zero-init visible

  // ---- prologue: emb(0); L0(0) ----
  if (w < 4){
    f32x4 e0 = MFMA16(cvt8(x0a,x0b), wembf, sp(eb));
    if (quad < 2){
#pragma unroll
      for (int r=0; r<4; ++r) XA[0][quad*4+r][ue] = (__bf16)e0[r];
    }
  }
  __syncthreads();
  { // pre-G: gates L0(0) (h0(-1)=0 cols are zeroed)
    bf16x8 ax0 = AFR(0,0,0), ax1 = AFR(0,0,1);
    bf16x8 ah0 = AFR(0,64,0), ah1 = AFR(0,64,1);
    f32x4 A00 = sp(gbias[0][0]), A01 = sp(gbias[0][1]);
    A00 = MFMA16(ax0, wf[0][0][0], A00); A01 = MFMA16(ax0, wf[0][1][0], A01);
    A00 = MFMA16(ax1, wf[0][0][1], A00); A01 = MFMA16(ax1, wf[0][1][1], A01);
    A00 = MFMA16(ah0, wf[0][0][2], A00); A01 = MFMA16(ah0, wf[0][1][2], A01);
    A00 = MFMA16(ah1, wf[0][0][3], A00); A01 = MFMA16(ah1, wf[0][1][3], A01);
    if (quad < 2){
#pragma unroll
      for (int r=0; r<4; ++r){ GL0[quad*4+r][n0] = A00[r]; GL0[quad*4+r][n1] = A01[r]; }
    }
  }
  __syncthreads();
  { // pre-E: h0(0) -> XA[0].h0 ; emb(1) -> XA[0].x
    float i0 = sigm (GL0[w][lane]);
    float f0 = sigm (GL0[w][64+lane]);
    float g0 = tanhx(GL0[w][128+lane]);
    float o0 = sigm (GL0[w][192+lane]);
    c0 = f0*c0 + i0*g0;
    XA[0][w][64+lane] = (__bf16)(o0 * tanhx(c0));
    if (w < 4){
      f32x4 e1 = MFMA16(cvt8(x1a,x1b), wembf, sp(eb));
      if (quad < 2){
#pragma unroll
        for (int r=0; r<4; ++r) XA[0][quad*4+r][ue] = (__bf16)e1[r];
      }
    }
  }
  __syncthreads();

  // ---- steady encoder: iter i computes [L1(i), L0(i+1)], 2 barriers/iter ----
#define STEP(I, PP)                                                            \
  {                                                                            \
    const int q_ = (PP)^1;                                                     \
    bf16x8 ax0 = AFR(PP,   0, 0), ax1 = AFR(PP,   0, 1);                       \
    bf16x8 ah0 = AFR(PP,  64, 0), ah1 = AFR(PP,  64, 1);                       \
    bf16x8 ag0 = AFR(PP, 128, 0), ag1 = AFR(PP, 128, 1);                       \
    f32x4 A00 = sp(gbias[0][0]), A01 = sp(gbias[0][1]);                        \
    f32x4 A10 = sp(gbias[1][0]), A11 = sp(gbias[1][1]);                        \
    A00 = MFMA16(ax0, wf[0][0][0], A00); A01 = MFMA16(ax0, wf[0][1][0], A01);  \
    A10 = MFMA16(ah0, wf[1][0][0], A10); A11 = MFMA16(ah0, wf[1][1][0], A11);  \
    A00 = MFMA16(ax1, wf[0][0][1], A00); A01 = MFMA16(ax1, wf[0][1][1], A01);  \
    A10 = MFMA16(ah1, wf[1][0][1], A10); A11 = MFMA16(ah1, wf[1][1][1], A11);  \
    A00 = MFMA16(ah0, wf[0][0][2], A00); A01 = MFMA16(ah0, wf[0][1][2], A01);  \
    A10 = MFMA16(ag0, wf[1][0][2], A10); A11 = MFMA16(ag0, wf[1][1][2], A11);  \
    A00 = MFMA16(ah1, wf[0][0][3], A00); A01 = MFMA16(ah1, wf[0][1][3], A01);  \
    A10 = MFMA16(ag1, wf[1][0][3], A10); A11 = MFMA16(ag1, wf[1][1][3], A11);  \
    f32x4 ea;                                                                  \
    if (w < 4){                                                                \
      const int s_ = (I)&1;                                                    \
      ea = MFMA16(cvt8(pa[s_],pb[s_]), wembf, sp(eb));                         \
      int tn_ = (I)+4; if (tn_ > 511) tn_ = 511;                               \
      pa[s_] = *(const f32x4*)(xb + (size_t)tn_*32);                           \
      pb[s_] = *(const f32x4*)(xb + (size_t)tn_*32 + 4);                       \
    }                                                                          \
    if (quad < 2){                                                             \
      _Pragma("unroll")                                                        \
      for (int r=0; r<4; ++r){                                                 \
        GL0[quad*4+r][n0] = A00[r]; GL0[quad*4+r][n1] = A01[r];                \
        GL1[quad*4+r][n0] = A10[r]; GL1[quad*4+r][n1] = A11[r];                \
      }                                                                        \
      if (w < 4){                                                              \
        _Pragma("unroll")                                                      \
        for (int r=0; r<4; ++r) XA[q_][quad*4+r][ue] = (__bf16)ea[r];          \
      }                                                                        \
    }                                                                          \
    __syncthreads();                                                           \
    {                                                                          \
      float i0 = sigm (GL0[w][lane]);                                          \
      float f0 = sigm (GL0[w][64+lane]);                                       \
      float g0 = tanhx(GL0[w][128+lane]);                                      \
      float o0 = sigm (GL0[w][192+lane]);                                      \
      float i1 = sigm (GL1[w][lane]);                                          \
      float f1 = sigm (GL1[w][64+lane]);                                       \
      float g1 = tanhx(GL1[w][128+lane]);                                      \
      float o1 = sigm (GL1[w][192+lane]);                                      \
      c0 = f0*c0 + i0*g0;                                                      \
      c1 = f1*c1 + i1*g1;                                                      \
      XA[q_][w][64+lane]  = (__bf16)(o0 * tanhx(c0));  /* h0(I+1) */           \
      XA[q_][w][128+lane] = (__bf16)(o1 * tanhx(c1));  /* h1(I)   */           \
    }                                                                          \
    __syncthreads();                                                           \
  }

  for (int ii = 0; ii < 255; ++ii){
    STEP(2*ii,   0)
    STEP(2*ii+1, 1)
  }
  STEP(510, 0)                        // i = 0..510: L1(510), L0(511)

  // ---- epilogue: L1(511) from XA[1] ----
  {
    bf16x8 ah0 = AFR(1,64,0), ah1 = AFR(1,64,1);
    bf16x8 ag0 = AFR(1,128,0), ag1 = AFR(1,128,1);
    f32x4 A10 = sp(gbias[1][0]), A11 = sp(gbias[1][1]);
    A10 = MFMA16(ah0, wf[1][0][0], A10); A11 = MFMA16(ah0, wf[1][1][0], A11);
    A10 = MFMA16(ah1, wf[1][0][1], A10); A11 = MFMA16(ah1, wf[1][1][1], A11);
    A10 = MFMA16(ag0, wf[1][0][2], A10); A11 = MFMA16(ag0, wf[1][1][2], A11);
    A10 = MFMA16(ag1, wf[1][0][3], A10); A11 = MFMA16(ag1, wf[1][1][3], A11);
    if (quad < 2){
#pragma unroll
      for (int r=0; r<4; ++r){ GL1[quad*4+r][n0] = A10[r]; GL1[quad*4+r][n1] = A11[r]; }
    }
  }
  __syncthreads();
  {
    float i1 = sigm (GL1[w][lane]);
    float f1 = sigm (GL1[w][64+lane]);
    float g1 = tanhx(GL1[w][128+lane]);
    float o1 = sigm (GL1[w][192+lane]);
    c1 = f1*c1 + i1*g1;
    XA[1][w][128+lane] = (__bf16)(o1 * tanhx(c1));   // h1(511)
  }
  __syncthreads();

  // ---- decoder init: XA[0] = [input=h1_enc | h0_enc | h1_enc]; c=0 ----
  for (int idx = tid; idx < 8*192; idx += 512){
    int r = idx / 192, cc = idx % 192;
    XA[0][r][cc] = (cc < 64) ? XA[1][r][128+cc] : XA[1][r][cc];
  }
#pragma unroll
  for (int l=0; l<2; ++l)
#pragma unroll
    for (int ti=0; ti<2; ++ti){
      const int n = ti ? n1 : n0;
      gbias[l][ti] = dbih[l*256+n] + dbhh[l*256+n];
#pragma unroll
      for (int ks=0; ks<4; ++ks){
        const float* srcw = (ks < 2) ? dWih : dWhh;
        wf[l][ti][ks] = ld8(srcw + ((size_t)(l*256+n))*64 + (ks&1)*32 + quad*8);
      }
    }
  c0 = 0.f; c1 = 0.f;
  __syncthreads();

  // ---- decoder: feedback prevents pipelining; 4 barriers/t ----
  for (int t=0; t<48; ++t){
    { // P1: L0 gates
      bf16x8 ax0 = AFR(0,0,0), ax1 = AFR(0,0,1);
      bf16x8 ah0 = AFR(0,64,0), ah1 = AFR(0,64,1);
      f32x4 A00 = sp(gbias[0][0]), A01 = sp(gbias[0][1]);
      A00 = MFMA16(ax0, wf[0][0][0], A00); A01 = MFMA16(ax0, wf[0][1][0], A01);
      A00 = MFMA16(ax1, wf[0][0][1], A00); A01 = MFMA16(ax1, wf[0][1][1], A01);
      A00 = MFMA16(ah0, wf[0][0][2], A00); A01 = MFMA16(ah0, wf[0][1][2], A01);
      A00 = MFMA16(ah1, wf[0][0][3], A00); A01 = MFMA16(ah1, wf[0][1][3], A01);
      if (quad < 2){
#pragma unroll
        for (int r=0; r<4; ++r){ GL0[quad*4+r][n0] = A00[r]; GL0[quad*4+r][n1] = A01[r]; }
      }
    }
    __syncthreads();
    {
      float i0 = sigm (GL0[w][lane]);
      float f0 = sigm (GL0[w][64+lane]);
      float g0 = tanhx(GL0[w][128+lane]);
      float o0 = sigm (GL0[w][192+lane]);
      c0 = f0*c0 + i0*g0;
      XA[0][w][64+lane] = (__bf16)(o0 * tanhx(c0));
    }
    __syncthreads();
    { // P3: L1 gates
      bf16x8 ah0 = AFR(0,64,0), ah1 = AFR(0,64,1);
      bf16x8 ag0 = AFR(0,128,0), ag1 = AFR(0,128,1);
      f32x4 A10 = sp(gbias[1][0]), A11 = sp(gbias[1][1]);
      A10 = MFMA16(ah0, wf[1][0][0], A10); A11 = MFMA16(ah0, wf[1][1][0], A11);
      A10 = MFMA16(ah1, wf[1][0][1], A10); A11 = MFMA16(ah1, wf[1][1][1], A11);
      A10 = MFMA16(ag0, wf[1][0][2], A10); A11 = MFMA16(ag0, wf[1][1][2], A11);
      A10 = MFMA16(ag1, wf[1][0][3], A10); A11 = MFMA16(ag1, wf[1][1][3], A11);
      if (quad < 2){
#pragma unroll
        for (int r=0; r<4; ++r){ GL1[quad*4+r][n0] = A10[r]; GL1[quad*4+r][n1] = A11[r]; }
      }
    }
    __syncthreads();
    {
      float i1 = sigm (GL1[w][lane]);
      float f1 = sigm (GL1[w][64+lane]);
      float g1 = tanhx(GL1[w][128+lane]);
      float o1 = sigm (GL1[w][192+lane]);
      c1 = f1*c1 + i1*g1;
      __bf16 hb = (__bf16)(o1 * tanhx(c1));
      XA[0][w][128+lane] = hb;
      XA[0][w][lane]     = hb;          // feedback -> next L0 input
    }
    __syncthreads();
    if (w == 0){ // y = h1 @ Wreg^T + breg
      f32x4 ya = sp(rb);
#pragma unroll
      for (int ks=0; ks<2; ++ks){
        bf16x8 ah = *(const bf16x8*)&XA[0][row8][128 + ks*32 + quad*8];
        ya = MFMA16(ah, wr[ks], ya);
      }
      if (quad < 2 && col < 8){
#pragma unroll
        for (int r=0; r<4; ++r)
          out[((size_t)(b0 + quad*4 + r)*48 + t)*8 + col] = ya[r];
      }
    }
  }
#undef STEP
#undef AFR
}

extern "C" void kernel_launch(void* const* d_in, const int* in_sizes, int n_in,
                              void* d_out, int out_size, void* d_ws, size_t ws_size,
                              hipStream_t stream)
{
  (void)in_sizes; (void)n_in; (void)out_size; (void)d_ws; (void)ws_size;
  const float* X    = (const float*)d_in[0];
  const float* Wemb = (const float*)d_in[2];
  const float* bemb = (const float*)d_in[3];
  const float* eWih = (const float*)d_in[4];
  const float* eWhh = (const float*)d_in[5];
  const float* ebih = (const float*)d_in[6];
  const float* ebhh = (const float*)d_in[7];
  const float* dWih = (const float*)d_in[8];
  const float* dWhh = (const float*)d_in[9];
  const float* dbih = (const float*)d_in[10];
  const float* dbhh = (const float*)d_in[11];
  const float* Wreg = (const float*)d_in[12];
  const float* breg = (const float*)d_in[13];
  float* out = (float*)d_out;

  seq2seq_kernel<<<dim3(256), dim3(512), 0, stream>>>(
      X, Wemb, bemb, eWih, eWhh, ebih, ebhh,
      dWih, dWhh, dbih, dbhh, Wreg, breg, out);
}